// Round 1
// baseline (11359.152 us; speedup 1.0000x reference)
//
#include <hip/hip_runtime.h>
#include <math.h>

#define NTOK 4096          // B*T
#define CDIM 1024
#define FDIM 4096
#define VDIM 50257
#define LNUM 2
#define NEXP 3
#define NRR  2

#define BM 128
#define BN 128
#define BK 16

__device__ __forceinline__ float sigf(float x) { return 1.0f / (1.0f + expf(-x)); }

template<int ACT> __device__ __forceinline__ float actfn(float x) {
    if constexpr (ACT == 1) { float t = fmaxf(x, 0.0f); return t * t; }           // relu^2
    else if constexpr (ACT == 2) {                                                 // tanh-gelu (jax approximate)
        float x3 = x * x * x;
        return 0.5f * x * (1.0f + tanhf(0.7978845608028654f * (x + 0.044715f * x3)));
    }
    return x;
}

// ---------------- embedding gather ----------------
__global__ __launch_bounds__(256) void embed_kernel(const int* __restrict__ idx,
                                                    const float* __restrict__ emb,
                                                    float* __restrict__ x) {
    int n = blockIdx.x;
    int t = threadIdx.x;
    const float4* s = reinterpret_cast<const float4*>(emb + (size_t)idx[n] * CDIM);
    float4* d = reinterpret_cast<float4*>(x + (size_t)n * CDIM);
    d[t] = s[t];
}

// ---------------- layernorm over C=1024 (one block per row) ----------------
__global__ __launch_bounds__(256) void ln_kernel(const float* __restrict__ x,
                                                 const float* __restrict__ s,
                                                 const float* __restrict__ b,
                                                 float* __restrict__ o) {
    __shared__ float sm[4];
    int row = blockIdx.x, t = threadIdx.x;
    int wave = t >> 6, lane = t & 63;
    float4 v = reinterpret_cast<const float4*>(x + (size_t)row * CDIM)[t];
    float p = v.x + v.y + v.z + v.w;
    #pragma unroll
    for (int off = 32; off; off >>= 1) p += __shfl_down(p, off);
    if (lane == 0) sm[wave] = p;
    __syncthreads();
    float mean = (sm[0] + sm[1] + sm[2] + sm[3]) * (1.0f / CDIM);
    __syncthreads();
    float4 xm = make_float4(v.x - mean, v.y - mean, v.z - mean, v.w - mean);
    p = xm.x * xm.x + xm.y * xm.y + xm.z * xm.z + xm.w * xm.w;
    #pragma unroll
    for (int off = 32; off; off >>= 1) p += __shfl_down(p, off);
    if (lane == 0) sm[wave] = p;
    __syncthreads();
    float rstd = 1.0f / sqrtf((sm[0] + sm[1] + sm[2] + sm[3]) * (1.0f / CDIM) + 1e-5f);
    float4 sv = reinterpret_cast<const float4*>(s)[t];
    float4 bv = reinterpret_cast<const float4*>(b)[t];
    float4 ov = make_float4(xm.x * rstd * sv.x + bv.x,
                            xm.y * rstd * sv.y + bv.y,
                            xm.z * rstd * sv.z + bv.z,
                            xm.w * rstd * sv.w + bv.w);
    reinterpret_cast<float4*>(o + (size_t)row * CDIM)[t] = ov;
}

// ---------------- v = v + (v_first - v)*sigmoid(g) ----------------
__global__ __launch_bounds__(256) void vmix_kernel(float* __restrict__ v,
                                                   const float* __restrict__ vf,
                                                   const float* __restrict__ g) {
    size_t i = (size_t)blockIdx.x * 256 + threadIdx.x;
    float4 vv = reinterpret_cast<const float4*>(v)[i];
    float4 fv = reinterpret_cast<const float4*>(vf)[i];
    float4 gv = reinterpret_cast<const float4*>(g)[i];
    vv.x += (fv.x - vv.x) * sigf(gv.x);
    vv.y += (fv.y - vv.y) * sigf(gv.y);
    vv.z += (fv.z - vv.z) * sigf(gv.z);
    vv.w += (fv.w - vv.w) * sigf(gv.w);
    reinterpret_cast<float4*>(v)[i] = vv;
}

// ---------------- u = sigmoid(r)*k*v (into r), state = k*v (into st) ----------------
__global__ __launch_bounds__(256) void ustate_kernel(float* __restrict__ r,
                                                     const float* __restrict__ k,
                                                     const float* __restrict__ v,
                                                     float* __restrict__ st) {
    size_t i = (size_t)blockIdx.x * 256 + threadIdx.x;
    float4 rv = reinterpret_cast<const float4*>(r)[i];
    float4 kv = reinterpret_cast<const float4*>(k)[i];
    float4 vv = reinterpret_cast<const float4*>(v)[i];
    float4 u4, s4;
    u4.x = sigf(rv.x) * kv.x * vv.x;  s4.x = kv.x * vv.x;
    u4.y = sigf(rv.y) * kv.y * vv.y;  s4.y = kv.y * vv.y;
    u4.z = sigf(rv.z) * kv.z * vv.z;  s4.z = kv.z * vv.z;
    u4.w = sigf(rv.w) * kv.w * vv.w;  s4.w = kv.w * vv.w;
    reinterpret_cast<float4*>(r)[i]  = u4;
    reinterpret_cast<float4*>(st)[i] = s4;
}

// ---------------- router: bids, argmax winner, scale, dispatch lists ----------------
__global__ __launch_bounds__(256) void router_kernel(
    const float* __restrict__ h, const float* __restrict__ cr0, const float* __restrict__ cr1,
    const float* __restrict__ ctv, const float* __restrict__ Wa, const float* __restrict__ sh,
    float* __restrict__ scaleA, int* __restrict__ lists, int* __restrict__ counts)
{
    int token = blockIdx.x * 4 + (threadIdx.x >> 6);
    int lane = threadIdx.x & 63;
    const float* hr = h + (size_t)token * CDIM;
    float d0=0,d1=0,d2=0,a0=0,a1=0,a2=0;
    for (int c = lane; c < CDIM; c += 64) {
        float hv = hr[c];
        d0 = fmaf(hv, cr0[c], d0);
        d1 = fmaf(hv, cr1[c], d1);
        d2 = fmaf(hv, ctv[c], d2);
        a0 = fmaf(hv, Wa[c*3+0], a0);
        a1 = fmaf(hv, Wa[c*3+1], a1);
        a2 = fmaf(hv, Wa[c*3+2], a2);
    }
    #pragma unroll
    for (int off = 32; off; off >>= 1) {
        d0 += __shfl_down(d0, off); d1 += __shfl_down(d1, off); d2 += __shfl_down(d2, off);
        a0 += __shfl_down(a0, off); a1 += __shfl_down(a1, off); a2 += __shfl_down(a2, off);
    }
    if (lane == 0) {
        float c0 = sigf(d0), c1 = sigf(d1), c2 = sigf(d2);
        float b0 = c0 * sh[0] + 0.1f * a0;
        float b1 = c1 * sh[1] + 0.1f * a1;
        float b2 = c2 * sh[2] + 0.1f * a2;
        int w = 0; float best = b0; float wc = c0;
        if (b1 > best) { best = b1; w = 1; wc = c1; }   // strict > : first-max, matches jnp.argmax
        if (b2 > best) { best = b2; w = 2; wc = c2; }
        scaleA[token] = wc / (wc + 1e-6f);
        int pos = atomicAdd(&counts[w], 1);
        lists[w * NTOK + pos] = token;
    }
}

// ---------------- fp32 SGEMM: C = [Res +] [scale *] act(A @ B) ----------------
// 128x128x16 tile, 256 threads, 8x8 microtile (split 4+4).
// GATHER: A rows via rowlist (input gather), C rows compact [0,cnt)
// SCATTER: A rows compact, C rows via rowlist, multiply by scaleA[row]
// NGUARD: guard N (column) bounds (head GEMM, V=50257); scalar B loads/stores (odd row stride)
template<int ACT, bool RESID, bool GATHER, bool SCATTER, bool NGUARD>
__global__ __launch_bounds__(256) void sgemm_kernel(
    const float* __restrict__ A, const float* __restrict__ Bm, float* Cm,
    const float* Res, int M, int N, int K,
    const int* __restrict__ rowlist, const int* __restrict__ counts,
    const float* __restrict__ scaleA)
{
    __shared__ float As[BK][BM + 4];
    __shared__ float Bs[BK][BN + 4];

    int effM = M;
    if constexpr (GATHER || SCATTER) effM = counts[0];
    const int by = blockIdx.y, bx = blockIdx.x;
    if (by * BM >= effM) return;

    const int tid  = threadIdx.x;
    const int tx   = tid & 15, ty = tid >> 4;
    const int arow = tid >> 2, ac4 = tid & 3;
    const int brow = tid >> 5;
    const int bcol = (tid & 31) * 4;

    const float* aptr0; const float* aptr1;
    {
        int i0 = by * BM + arow, i1 = i0 + 64;
        if constexpr (GATHER) {
            if (i0 >= effM) i0 = effM - 1;
            if (i1 >= effM) i1 = effM - 1;
            i0 = rowlist[i0]; i1 = rowlist[i1];
        } else if constexpr (SCATTER) {
            if (i0 >= effM) i0 = effM - 1;
            if (i1 >= effM) i1 = effM - 1;
        }
        aptr0 = A + (size_t)i0 * K + ac4 * 4;
        aptr1 = A + (size_t)i1 * K + ac4 * 4;
    }
    const int bcol_g = bx * BN + bcol;
    const float* bptr0 = Bm + (size_t)brow * N + bcol_g;
    const float* bptr1 = Bm + (size_t)(brow + 8) * N + bcol_g;

    float acc[8][8];
    #pragma unroll
    for (int i = 0; i < 8; ++i)
        #pragma unroll
        for (int j = 0; j < 8; ++j) acc[i][j] = 0.0f;

    auto loadB = [&](const float* p) -> float4 {
        if constexpr (!NGUARD) {
            return *reinterpret_cast<const float4*>(p);
        } else {
            float4 r;
            r.x = (bcol_g + 0 < N) ? p[0] : 0.0f;
            r.y = (bcol_g + 1 < N) ? p[1] : 0.0f;
            r.z = (bcol_g + 2 < N) ? p[2] : 0.0f;
            r.w = (bcol_g + 3 < N) ? p[3] : 0.0f;
            return r;
        }
    };

    const int nk = K / BK;
    float4 pa0 = *reinterpret_cast<const float4*>(aptr0);
    float4 pa1 = *reinterpret_cast<const float4*>(aptr1);
    float4 pb0 = loadB(bptr0);
    float4 pb1 = loadB(bptr1);

    for (int kt = 0; kt < nk; ++kt) {
        __syncthreads();
        As[ac4*4 + 0][arow]      = pa0.x;
        As[ac4*4 + 1][arow]      = pa0.y;
        As[ac4*4 + 2][arow]      = pa0.z;
        As[ac4*4 + 3][arow]      = pa0.w;
        As[ac4*4 + 0][arow + 64] = pa1.x;
        As[ac4*4 + 1][arow + 64] = pa1.y;
        As[ac4*4 + 2][arow + 64] = pa1.z;
        As[ac4*4 + 3][arow + 64] = pa1.w;
        *reinterpret_cast<float4*>(&Bs[brow][bcol])     = pb0;
        *reinterpret_cast<float4*>(&Bs[brow + 8][bcol]) = pb1;
        __syncthreads();
        if (kt + 1 < nk) {
            aptr0 += BK; aptr1 += BK;
            bptr0 += (size_t)BK * N; bptr1 += (size_t)BK * N;
            pa0 = *reinterpret_cast<const float4*>(aptr0);
            pa1 = *reinterpret_cast<const float4*>(aptr1);
            pb0 = loadB(bptr0);
            pb1 = loadB(bptr1);
        }
        #pragma unroll
        for (int k = 0; k < BK; ++k) {
            float4 a0 = *reinterpret_cast<const float4*>(&As[k][ty * 4]);
            float4 a1 = *reinterpret_cast<const float4*>(&As[k][64 + ty * 4]);
            float4 b0 = *reinterpret_cast<const float4*>(&Bs[k][tx * 4]);
            float4 b1 = *reinterpret_cast<const float4*>(&Bs[k][64 + tx * 4]);
            float av[8] = {a0.x,a0.y,a0.z,a0.w,a1.x,a1.y,a1.z,a1.w};
            float bv[8] = {b0.x,b0.y,b0.z,b0.w,b1.x,b1.y,b1.z,b1.w};
            #pragma unroll
            for (int i = 0; i < 8; ++i)
                #pragma unroll
                for (int j = 0; j < 8; ++j)
                    acc[i][j] = fmaf(av[i], bv[j], acc[i][j]);
        }
    }

    // epilogue
    #pragma unroll
    for (int ih = 0; ih < 2; ++ih) {
        #pragma unroll
        for (int ii = 0; ii < 4; ++ii) {
            int i = ih * 4 + ii;
            int r = by * BM + ih * 64 + ty * 4 + ii;
            if constexpr (GATHER || SCATTER) { if (r >= effM) continue; }
            int orow = r;
            float sc = 1.0f;
            if constexpr (SCATTER) { orow = rowlist[r]; sc = scaleA[orow]; }
            float* crow = Cm + (size_t)orow * N;
            const float* rrow = RESID ? (Res + (size_t)orow * N) : nullptr;
            #pragma unroll
            for (int jh = 0; jh < 2; ++jh) {
                int c = bx * BN + jh * 64 + tx * 4;
                float vals[4];
                #pragma unroll
                for (int jj = 0; jj < 4; ++jj) {
                    float v = actfn<ACT>(acc[i][jh * 4 + jj]);
                    if constexpr (SCATTER) v *= sc;
                    vals[jj] = v;
                }
                if constexpr (!NGUARD) {
                    float4 o = make_float4(vals[0], vals[1], vals[2], vals[3]);
                    if constexpr (RESID) {
                        float4 rv = *reinterpret_cast<const float4*>(rrow + c);
                        o.x += rv.x; o.y += rv.y; o.z += rv.z; o.w += rv.w;
                    }
                    *reinterpret_cast<float4*>(crow + c) = o;
                } else {
                    #pragma unroll
                    for (int jj = 0; jj < 4; ++jj)
                        if (c + jj < N) crow[c + jj] = vals[jj];
                }
            }
        }
    }
}

extern "C" void kernel_launch(void* const* d_in, const int* in_sizes, int n_in,
                              void* d_out, int out_size, void* d_ws, size_t ws_size,
                              hipStream_t stream)
{
    const int*   idx    = (const int*)d_in[0];
    const float* emb    = (const float*)d_in[1];
    const float* ln1_s  = (const float*)d_in[2];
    const float* ln1_b  = (const float*)d_in[3];
    const float* ln2_s  = (const float*)d_in[4];
    const float* ln2_b  = (const float*)d_in[5];
    const float* Wr     = (const float*)d_in[6];
    const float* Wk     = (const float*)d_in[7];
    const float* Wv     = (const float*)d_in[8];
    const float* Wg     = (const float*)d_in[9];
    const float* Wo     = (const float*)d_in[10];
    const float* W1r    = (const float*)d_in[11];
    const float* W2r    = (const float*)d_in[12];
    const float* cr     = (const float*)d_in[13];
    const float* Wsm    = (const float*)d_in[14];
    const float* Wt1    = (const float*)d_in[15];
    const float* Wt2    = (const float*)d_in[16];
    const float* ct     = (const float*)d_in[17];
    const float* Wa     = (const float*)d_in[18];
    /* d_in[19] = Wb, unused by reference */
    const float* shares = (const float*)d_in[20];
    const float* lno_s  = (const float*)d_in[21];
    const float* lno_b  = (const float*)d_in[22];
    const float* headW  = (const float*)d_in[23];
    float* out = (float*)d_out;

    // workspace layout (floats) — ~201 MB total
    const size_t NC = (size_t)NTOK * CDIM;
    float* ws     = (float*)d_ws;
    float* xbuf   = ws;                              // residual stream x
    float* nrm    = xbuf + NC;                       // xn / h / xo
    float* rbuf   = nrm + NC;                        // r then u
    float* kbuf   = rbuf + NC;
    float* vbuf   = kbuf + NC;
    float* vfirst = vbuf + NC;
    float* stbuf  = vfirst + NC;                     // g then state
    float* zbuf   = stbuf + NC;                      // h + state@Ws
    float* hidden = zbuf + NC;                       // N x F expert hidden
    float* scaleA = hidden + (size_t)NTOK * FDIM;
    int*   lists  = (int*)(scaleA + NTOK);
    int*   counts = lists + NEXP * NTOK;

    const int vec_blocks = (NTOK * CDIM / 4) / 256;  // 4096

    embed_kernel<<<NTOK, 256, 0, stream>>>(idx, emb, xbuf);

    dim3 gCC(CDIM / BN, NTOK / BM);                  // 8 x 32   (K = C)
    dim3 gCF(FDIM / BN, NTOK / BM);                  // 32 x 32  (K = C)
    dim3 gFC(CDIM / BN, NTOK / BM);                  // 8 x 32   (K = F)
    dim3 gHead((VDIM + BN - 1) / BN, NTOK / BM);     // 393 x 32

    for (int l = 0; l < LNUM; ++l) {
        const float* Wr_l  = Wr  + (size_t)l * CDIM * CDIM;
        const float* Wk_l  = Wk  + (size_t)l * CDIM * CDIM;
        const float* Wv_l  = Wv  + (size_t)l * CDIM * CDIM;
        const float* Wg_l  = Wg  + (size_t)l * CDIM * CDIM;
        const float* Wo_l  = Wo  + (size_t)l * CDIM * CDIM;
        const float* Ws_l  = Wsm + (size_t)l * CDIM * CDIM;
        const float* Wt1_l = Wt1 + (size_t)l * CDIM * FDIM;
        const float* Wt2_l = Wt2 + (size_t)l * FDIM * CDIM;

        // xn = LN1(x)
        ln_kernel<<<NTOK, 256, 0, stream>>>(xbuf, ln1_s + l * CDIM, ln1_b + l * CDIM, nrm);
        // r, k, v
        sgemm_kernel<0,false,false,false,false><<<gCC,256,0,stream>>>(nrm, Wr_l, rbuf, nullptr, NTOK, CDIM, CDIM, nullptr, nullptr, nullptr);
        sgemm_kernel<0,false,false,false,false><<<gCC,256,0,stream>>>(nrm, Wk_l, kbuf, nullptr, NTOK, CDIM, CDIM, nullptr, nullptr, nullptr);
        sgemm_kernel<0,false,false,false,false><<<gCC,256,0,stream>>>(nrm, Wv_l, vbuf, nullptr, NTOK, CDIM, CDIM, nullptr, nullptr, nullptr);
        if (l == 0) {
            hipMemcpyAsync(vfirst, vbuf, NC * sizeof(float), hipMemcpyDeviceToDevice, stream);
        } else {
            sgemm_kernel<0,false,false,false,false><<<gCC,256,0,stream>>>(nrm, Wg_l, stbuf, nullptr, NTOK, CDIM, CDIM, nullptr, nullptr, nullptr);
            vmix_kernel<<<vec_blocks, 256, 0, stream>>>(vbuf, vfirst, stbuf);
        }
        // u = sigmoid(r)*k*v (into rbuf), state = k*v (into stbuf)
        ustate_kernel<<<vec_blocks, 256, 0, stream>>>(rbuf, kbuf, vbuf, stbuf);
        // x = x + u @ Wo (in-place residual: each element read+written by exactly one thread)
        sgemm_kernel<0,true,false,false,false><<<gCC,256,0,stream>>>(rbuf, Wo_l, xbuf, xbuf, NTOK, CDIM, CDIM, nullptr, nullptr, nullptr);
        // h = LN2(x)
        ln_kernel<<<NTOK, 256, 0, stream>>>(xbuf, ln2_s + l * CDIM, ln2_b + l * CDIM, nrm);
        // router
        hipMemsetAsync(counts, 0, NEXP * sizeof(int), stream);
        router_kernel<<<NTOK / 4, 256, 0, stream>>>(nrm,
            cr + ((size_t)l * NRR + 0) * CDIM, cr + ((size_t)l * NRR + 1) * CDIM,
            ct + (size_t)l * CDIM, Wa + (size_t)l * CDIM * NEXP, shares + l * NEXP,
            scaleA, lists, counts);
        // z = h + state @ Ws  (input for transformer expert)
        sgemm_kernel<0,true,false,false,false><<<gCC,256,0,stream>>>(stbuf, Ws_l, zbuf, nrm, NTOK, CDIM, CDIM, nullptr, nullptr, nullptr);
        // relu^2 experts 0,1 (routed)
        for (int e = 0; e < NRR; ++e) {
            const float* W1 = W1r + ((size_t)l * NRR + e) * CDIM * FDIM;
            const float* W2 = W2r + ((size_t)l * NRR + e) * FDIM * CDIM;
            sgemm_kernel<1,false,true,false,false><<<gCF,256,0,stream>>>(nrm, W1, hidden, nullptr, NTOK, FDIM, CDIM, lists + e * NTOK, counts + e, nullptr);
            sgemm_kernel<0,true,false,true,false><<<gFC,256,0,stream>>>(hidden, W2, xbuf, xbuf, NTOK, CDIM, FDIM, lists + e * NTOK, counts + e, scaleA);
        }
        // transformer expert (e=2), gelu, input z
        sgemm_kernel<2,false,true,false,false><<<gCF,256,0,stream>>>(zbuf, Wt1_l, hidden, nullptr, NTOK, FDIM, CDIM, lists + 2 * NTOK, counts + 2, nullptr);
        sgemm_kernel<0,true,false,true,false><<<gFC,256,0,stream>>>(hidden, Wt2_l, xbuf, xbuf, NTOK, CDIM, FDIM, lists + 2 * NTOK, counts + 2, scaleA);
    }
    // logits = LN(x) @ headW
    ln_kernel<<<NTOK, 256, 0, stream>>>(xbuf, lno_s, lno_b, nrm);
    sgemm_kernel<0,false,false,false,true><<<gHead,256,0,stream>>>(nrm, headW, out, nullptr, NTOK, VDIM, CDIM, nullptr, nullptr, nullptr);
}